// Round 4
// baseline (230.822 us; speedup 1.0000x reference)
//
#include <hip/hip_runtime.h>
#include <hip/hip_bf16.h>

// Chunked simple-GLA forward, B=2 H=32 T=4096 K=V=128, BT=64.
// grid = 64 (b,h) x 4 v-segments, 512 threads (8 waves).
// State slice S [128 kd x 32 vc] lives in MFMA accumulators.
// P1: QK^T+gating+state-update ; P2: o_inter+o_intra+store+stage(n+1).
// k_s single-buffered (swizzled); q fragments direct from global.

#define BT 64
#define KD 128
#define VD 128
#define VSG 32
#define NCHUNK 64
#define TLEN 4096
#define SCALE 0.08838834764831845f   // 128^-0.5

#define QSTR 136   // k_s row stride (elems); rows 272B -> b128 even-spread
#define SHSTR 72
#define SVSTR 136
#define VTSTR 72

typedef __bf16 bf16;
typedef __bf16 bf16x8 __attribute__((ext_vector_type(8)));
typedef __bf16 bf16x4 __attribute__((ext_vector_type(4)));
typedef float f32x4 __attribute__((ext_vector_type(4)));

#define MFMA __builtin_amdgcn_mfma_f32_16x16x32_bf16
#define LGKM_BARRIER() do { asm volatile("s_waitcnt lgkmcnt(0)" ::: "memory"); \
                            __builtin_amdgcn_s_barrier(); } while (0)

// k_s byte swizzle: key (t>>3)&3 == lane-group of the column reads -> 2-way
__device__ __forceinline__ int ksw(int t) { return ((t >> 3) & 3) << 5; }

// vT/vwT swizzle (validated in R2): conflict-free transposed stores, b128 reads
__device__ __forceinline__ int vt_off(int vc, int t) {
  int byte = vc * (VTSTR * 2) + t * 2;
  byte ^= ((vc >> 2) & 7) << 4;
  return byte >> 1;
}

// generic row fragment (non-swizzled arrays: svt, sh)
__device__ __forceinline__ bf16x8 frag_row(const bf16* p, int stride, int row0,
                                           int kk0, int lane) {
  int row = row0 + (lane & 15);
  int kk = kk0 + ((lane >> 4) << 3);
  return *(const bf16x8*)(p + row * stride + kk);
}

// swizzled k_s row fragment (QK^T A operand)
__device__ __forceinline__ bf16x8 krow_frag(const bf16* ks_, int row0, int kk0,
                                            int lane) {
  int row = row0 + (lane & 15);
  int kk = kk0 + ((lane >> 4) << 3);
  int byte = (row * (QSTR * 2) + kk * 2) ^ ksw(row);
  return *(const bf16x8*)((const char*)ks_ + byte);
}

// swizzled k_s column fragment (state-update A operand), 8 scalar 2-way reads
__device__ __forceinline__ bf16x8 kcol_frag(const bf16* ks_, int T0, int kdA) {
  int C = ((T0 >> 3) & 3) << 5;
  int b0 = T0 * (QSTR * 2) + kdA * 2;
  bf16x8 f;
#pragma unroll
  for (int j = 0; j < 8; ++j)
    f[j] = *(const bf16*)((const char*)ks_ + ((b0 + j * (QSTR * 2)) ^ C));
  return f;
}

__device__ __forceinline__ void st4(bf16* p, float a, float b, float c, float d) {
  bf16x4 t;
  t[0] = (bf16)a; t[1] = (bf16)b; t[2] = (bf16)c; t[3] = (bf16)d;
  *(bf16x4*)p = t;
}

__global__ void __launch_bounds__(512, 2)
gla_fused(const float* __restrict__ qg, const float* __restrict__ kg,
          const float* __restrict__ vg, const float* __restrict__ gg,
          float* __restrict__ og)
{
  __shared__ __align__(16) bf16 k_s[BT * QSTR];        // swizzled, single buf
  __shared__ __align__(16) bf16 vT_s[2][VSG * VTSTR];  // v^T [vc][t]
  __shared__ __align__(16) bf16 vwT_s[2][VSG * VTSTR]; // (v*w)^T [vc][t]
  __shared__ __align__(16) bf16 sh_s[BT * SHSTR];      // gated s-hat [i][j]
  __shared__ __align__(16) bf16 svt_s[VSG * SVSTR];    // h_n slice [vc][kd]
  __shared__ __align__(16) float gc_s[2][BT], w_s[2][BT], egc_s[2][BT];
  __shared__ float decay_s[2];

  const int tid = threadIdx.x;
  const int wave = tid >> 6;
  const int lane = tid & 63;
  const int bh = blockIdx.x & 63;   // 4 vseg blocks of one bh share an XCD
  const int vseg = blockIdx.x >> 6;

  const int jc = lane & 15;
  const int g4 = lane >> 4;
  const int r0 = g4 << 2;

  const int it = wave & 3;             // q-token tile (s cols, o rows)
  const int nt = wave >> 2;            // o vcol tile
  const int jt0 = (wave < 4) ? 0 : 2;  // k-token tiles {jt0, jt0+1}

  const size_t qkbase = (size_t)bh * TLEN * KD;
  const size_t gbase = (size_t)bh * TLEN;
  const size_t vbase = (size_t)bh * TLEN * VD + (size_t)vseg * VSG;
  const int vrow = tid >> 3;
  const int vc0 = (tid & 7) << 2;

  float4 kpf[4], vpf, qf[8];

  auto load_kv = [&](int n) {
    const float4* k4 = (const float4*)(kg + qkbase + (size_t)n * (BT * KD));
#pragma unroll
    for (int i = 0; i < 4; ++i) kpf[i] = k4[i * 512 + tid];
    vpf = *(const float4*)(vg + vbase + (size_t)(n * BT + vrow) * VD + vc0);
  };
  auto load_q = [&](int n) {
    const float* qn = qg + qkbase + (size_t)n * (BT * KD)
                    + (size_t)(it * 16 + jc) * KD + (g4 << 3);
#pragma unroll
    for (int ks = 0; ks < 4; ++ks) {
      qf[2 * ks]     = *(const float4*)(qn + ks * 32);
      qf[2 * ks + 1] = *(const float4*)(qn + ks * 32 + 4);
    }
  };
  auto scan = [&](int buf, int n) {  // wave 0 only
    float a = gg[gbase + n * BT + lane];
#pragma unroll
    for (int off = 1; off < 64; off <<= 1) {
      float t = __shfl_up(a, off);
      if (lane >= off) a += t;
    }
    float glast = __shfl(a, 63);
    gc_s[buf][lane] = a;
    w_s[buf][lane] = __expf(glast - a);
    egc_s[buf][lane] = __expf(a) * SCALE;
    if (lane == 0) decay_s[buf] = __expf(glast);
  };
  auto stage = [&](int buf, int n) {  // k_s + vT/vwT[buf] from kpf/vpf + w_s[buf]
#pragma unroll
    for (int i = 0; i < 4; ++i) {
      int f4 = i * 512 + tid;
      int t = f4 >> 5;
      int kd0 = (f4 & 31) << 2;
      int byte = (t * (QSTR * 2) + kd0 * 2) ^ ksw(t);
      st4((bf16*)((char*)k_s + byte), kpf[i].x, kpf[i].y, kpf[i].z, kpf[i].w);
    }
    bf16* vt = &vT_s[buf][0];
    bf16* vwt = &vwT_s[buf][0];
    float wv = w_s[buf][vrow];
    vt[vt_off(vc0 + 0, vrow)] = (bf16)vpf.x;
    vt[vt_off(vc0 + 1, vrow)] = (bf16)vpf.y;
    vt[vt_off(vc0 + 2, vrow)] = (bf16)vpf.z;
    vt[vt_off(vc0 + 3, vrow)] = (bf16)vpf.w;
    vwt[vt_off(vc0 + 0, vrow)] = (bf16)(vpf.x * wv);
    vwt[vt_off(vc0 + 1, vrow)] = (bf16)(vpf.y * wv);
    vwt[vt_off(vc0 + 2, vrow)] = (bf16)(vpf.z * wv);
    vwt[vt_off(vc0 + 3, vrow)] = (bf16)(vpf.w * wv);
  };

  // state: Sa = S[kd = wave*16 + r0+r][vc = jc], Sb at vc = 16+jc
  f32x4 Sa = {0.f, 0.f, 0.f, 0.f}, Sb = {0.f, 0.f, 0.f, 0.f};

  // ---- prologue
  load_kv(0);
  load_q(0);
  if (wave == 0) scan(0, 0);
  LGKM_BARRIER();        // w_s[0] visible for staging
  stage(0, 0);
  LGKM_BARRIER();

  for (int n = 0; n < NCHUNK; ++n) {
    const int cur = n & 1;
    const int nxt = cur ^ 1;

    // ---------- phase 1 ----------
    bf16x8 af[4];  // q fragments for chunk n (B for QK^T, A for o_inter)
#pragma unroll
    for (int ks = 0; ks < 4; ++ks) {
      const float* a0 = (const float*)&qf[2 * ks];
      const float* a1 = (const float*)&qf[2 * ks + 1];
      bf16x8 a;
#pragma unroll
      for (int j = 0; j < 4; ++j) { a[j] = (bf16)a0[j]; a[4 + j] = (bf16)a1[j]; }
      af[ks] = a;
    }
    if (n + 1 < NCHUNK) {  // next-chunk loads: in flight across barriers
      load_q(n + 1);
      load_kv(n + 1);
      if (wave == 0) scan(nxt, n + 1);
    }

    // export pre-update state h_n (b64 stores)
    st4(&svt_s[jc * SVSTR + wave * 16 + r0], Sa[0], Sa[1], Sa[2], Sa[3]);
    st4(&svt_s[(16 + jc) * SVSTR + wave * 16 + r0], Sb[0], Sb[1], Sb[2], Sb[3]);

    // s^T = k q^T: lane holds rows j = jt*16+r0+r, col i = it*16+jc
    f32x4 sa0 = {0.f,0.f,0.f,0.f}, sa1 = {0.f,0.f,0.f,0.f};
#pragma unroll
    for (int ks = 0; ks < 4; ++ks) {
      bf16x8 a0 = krow_frag(k_s, jt0 * 16, ks * 32, lane);
      bf16x8 a1 = krow_frag(k_s, (jt0 + 1) * 16, ks * 32, lane);
      sa0 = MFMA(a0, af[ks], sa0, 0, 0, 0);
      sa1 = MFMA(a1, af[ks], sa1, 0, 0, 0);
    }
    {
      int i0 = it * 16 + jc;
      float gci = gc_s[cur][i0];
#pragma unroll
      for (int t = 0; t < 2; ++t) {
        f32x4 sv = t ? sa1 : sa0;
        int jb = (jt0 + t) * 16 + r0;
        float4 g4v = *(const float4*)&gc_s[cur][jb];
        const float* gj = (const float*)&g4v;
        bf16x4 pk;
#pragma unroll
        for (int r = 0; r < 4; ++r) {
          float val = (i0 >= jb + r) ? sv[r] * __expf(gci - gj[r]) * SCALE : 0.f;
          pk[r] = (bf16)val;
        }
        *(bf16x4*)&sh_s[i0 * SHSTR + jb] = pk;
      }
    }
    // state update: S = decay*S + k^T @ (v*w)  (A = k columns, B = vwT[cur])
    {
      float dec = decay_s[cur];
#pragma unroll
      for (int r = 0; r < 4; ++r) { Sa[r] *= dec; Sb[r] *= dec; }
#pragma unroll
      for (int ks = 0; ks < 2; ++ks) {
        bf16x8 a = kcol_frag(k_s, ks * 32 + (g4 << 3), wave * 16 + jc);
        bf16x8 b0 = *(const bf16x8*)(&vwT_s[cur][0] + vt_off(jc, ks * 32 + (g4 << 3)));
        bf16x8 b1 = *(const bf16x8*)(&vwT_s[cur][0] + vt_off(16 + jc, ks * 32 + (g4 << 3)));
        Sa = MFMA(a, b0, Sa, 0, 0, 0);
        Sb = MFMA(a, b1, Sb, 0, 0, 0);
      }
    }
    LGKM_BARRIER();

    // ---------- phase 2 ----------
    {
      f32x4 oacc = {0.f, 0.f, 0.f, 0.f};
#pragma unroll
      for (int ks = 0; ks < 4; ++ks) {  // o_inter = q @ h_n
        bf16x8 b = frag_row(svt_s, SVSTR, nt * 16, ks * 32, lane);
        oacc = MFMA(af[ks], b, oacc, 0, 0, 0);
      }
      {
        float4 e4 = *(const float4*)&egc_s[cur][it * 16 + r0];
        const float* ep = (const float*)&e4;
#pragma unroll
        for (int r = 0; r < 4; ++r) oacc[r] *= ep[r];
      }
#pragma unroll
      for (int ks = 0; ks < 2; ++ks) {  // o_intra = s-hat @ v
        bf16x8 a = frag_row(sh_s, SHSTR, it * 16, ks * 32, lane);
        bf16x8 b = *(const bf16x8*)(&vT_s[cur][0] + vt_off(nt * 16 + jc, ks * 32 + (g4 << 3)));
        oacc = MFMA(a, b, oacc, 0, 0, 0);
      }
#pragma unroll
      for (int r = 0; r < 4; ++r) {
        int row = it * 16 + r0 + r;
        og[vbase + (size_t)(n * BT + row) * VD + nt * 16 + jc] = oacc[r];
      }
    }
    if (n + 1 < NCHUNK) stage(nxt, n + 1);  // k_s free after P1's reads
    LGKM_BARRIER();
  }
}

extern "C" void kernel_launch(void* const* d_in, const int* in_sizes, int n_in,
                              void* d_out, int out_size, void* d_ws, size_t ws_size,
                              hipStream_t stream) {
  const float* q = (const float*)d_in[0];
  const float* k = (const float*)d_in[1];
  const float* v = (const float*)d_in[2];
  const float* g = (const float*)d_in[3];
  float* o = (float*)d_out;
  dim3 grid(256);   // 64 (b,h) x 4 v-segments
  dim3 block(512);  // 8 waves
  gla_fused<<<grid, block, 0, stream>>>(q, k, v, g, o);
}

// Round 5
// 186.049 us; speedup vs baseline: 1.2407x; 1.2407x over previous
//
#include <hip/hip_runtime.h>
#include <hip/hip_bf16.h>

// Chunked simple-GLA forward, B=2 H=32 T=4096 K=V=128, BT=64.
// grid = 64 (b,h) x 4 v-segments, 512 threads (8 waves).
// State slice S [128 kd x 32 vc] lives in MFMA accumulators.
// All 64 gate scans precomputed in a prologue (gc_all in LDS).
// P1: QK^T+gating+state-update ; P2: o_inter+o_intra+store+stage(n+1).

#define BT 64
#define KD 128
#define VD 128
#define VSG 32
#define NCHUNK 64
#define TLEN 4096
#define SCALE 0.08838834764831845f   // 128^-0.5

#define QSTR 136   // q_s/k_s row stride (elems)
#define SHSTR 72
#define SVSTR 136
#define VTSTR 72

typedef __bf16 bf16;
typedef __bf16 bf16x8 __attribute__((ext_vector_type(8)));
typedef __bf16 bf16x4 __attribute__((ext_vector_type(4)));
typedef float f32x4 __attribute__((ext_vector_type(4)));

#define MFMA __builtin_amdgcn_mfma_f32_16x16x32_bf16
#define LGKM_BARRIER() do { asm volatile("s_waitcnt lgkmcnt(0)" ::: "memory"); \
                            __builtin_amdgcn_s_barrier(); } while (0)

// k_s byte swizzle: key (t>>3)&3 == lane-group of the column reads -> 2-way
__device__ __forceinline__ int ksw(int t) { return ((t >> 3) & 3) << 5; }

// vT/vwT swizzle: conflict-free transposed stores, b128-aligned reads
__device__ __forceinline__ int vt_off(int vc, int t) {
  int byte = vc * (VTSTR * 2) + t * 2;
  byte ^= ((vc >> 2) & 7) << 4;
  return byte >> 1;
}

// row fragment (non-swizzled: q_s, svt, sh)
__device__ __forceinline__ bf16x8 frag_row(const bf16* p, int stride, int row0,
                                           int kk0, int lane) {
  int row = row0 + (lane & 15);
  int kk = kk0 + ((lane >> 4) << 3);
  return *(const bf16x8*)(p + row * stride + kk);
}

// swizzled k_s row fragment (QK^T A operand)
__device__ __forceinline__ bf16x8 krow_frag(const bf16* ks_, int row0, int kk0,
                                            int lane) {
  int row = row0 + (lane & 15);
  int kk = kk0 + ((lane >> 4) << 3);
  int byte = (row * (QSTR * 2) + kk * 2) ^ ksw(row);
  return *(const bf16x8*)((const char*)ks_ + byte);
}

// swizzled k_s column fragment (state-update A operand), 8 scalar 2-way reads
__device__ __forceinline__ bf16x8 kcol_frag(const bf16* ks_, int T0, int kdA) {
  int C = ((T0 >> 3) & 3) << 5;
  int b0 = T0 * (QSTR * 2) + kdA * 2;
  bf16x8 f;
#pragma unroll
  for (int j = 0; j < 8; ++j)
    f[j] = *(const bf16*)((const char*)ks_ + ((b0 + j * (QSTR * 2)) ^ C));
  return f;
}

__device__ __forceinline__ void st4(bf16* p, float a, float b, float c, float d) {
  bf16x4 t;
  t[0] = (bf16)a; t[1] = (bf16)b; t[2] = (bf16)c; t[3] = (bf16)d;
  *(bf16x4*)p = t;
}

__global__ void __launch_bounds__(512, 2)
gla_fused(const float* __restrict__ qg, const float* __restrict__ kg,
          const float* __restrict__ vg, const float* __restrict__ gg,
          float* __restrict__ og)
{
  __shared__ __align__(16) bf16 q_s[BT * QSTR];        // plain padded rows
  __shared__ __align__(16) bf16 k_s[BT * QSTR];        // XOR-swizzled rows
  __shared__ __align__(16) bf16 vT_s[2][VSG * VTSTR];  // v^T [vc][t]
  __shared__ __align__(16) bf16 vwT_s[2][VSG * VTSTR]; // (v*w)^T [vc][t]
  __shared__ __align__(16) bf16 sh_s[BT * SHSTR];      // gated s-hat [i][j]
  __shared__ __align__(16) bf16 svt_s[VSG * SVSTR];    // h_n slice [vc][kd]
  __shared__ __align__(16) float gc_all[NCHUNK][BT];   // chunk-local cumsum g
  __shared__ float glast_all[NCHUNK];

  const int tid = threadIdx.x;
  const int wave = tid >> 6;
  const int lane = tid & 63;
  const int bh = blockIdx.x & 63;   // 4 vseg blocks of one bh share an XCD
  const int vseg = blockIdx.x >> 6;

  const int jc = lane & 15;
  const int g4 = lane >> 4;
  const int r0 = g4 << 2;

  const int it = wave & 3;             // q-token tile (s cols, o rows)
  const int nt = wave >> 2;            // o vcol tile
  const int jt0 = (wave < 4) ? 0 : 2;  // k-token tiles {jt0, jt0+1}

  const size_t qkbase = (size_t)bh * TLEN * KD;
  const size_t gbase = (size_t)bh * TLEN;
  const size_t vbase = (size_t)bh * TLEN * VD + (size_t)vseg * VSG;
  const int vrow = tid >> 3;
  const int vc0 = (tid & 7) << 2;

  float4 qpf[4], kpf[4], vpf;

  auto loadpf = [&](int n) {  // coalesced: thread-contiguous float4
    const float4* q4 = (const float4*)(qg + qkbase + (size_t)n * (BT * KD));
    const float4* k4 = (const float4*)(kg + qkbase + (size_t)n * (BT * KD));
#pragma unroll
    for (int i = 0; i < 4; ++i) { qpf[i] = q4[i * 512 + tid]; kpf[i] = k4[i * 512 + tid]; }
    vpf = *(const float4*)(vg + vbase + (size_t)(n * BT + vrow) * VD + vc0);
  };

  auto stage = [&](int buf, int n) {  // q_s, k_s, vT/vwT[buf] for chunk n
#pragma unroll
    for (int i = 0; i < 4; ++i) {
      int f4 = i * 512 + tid;
      int t = f4 >> 5;
      int kd0 = (f4 & 31) << 2;
      st4(&q_s[t * QSTR + kd0], qpf[i].x, qpf[i].y, qpf[i].z, qpf[i].w);
      int byte = (t * (QSTR * 2) + kd0 * 2) ^ ksw(t);
      st4((bf16*)((char*)k_s + byte), kpf[i].x, kpf[i].y, kpf[i].z, kpf[i].w);
    }
    bf16* vt = &vT_s[buf][0];
    bf16* vwt = &vwT_s[buf][0];
    float wv = __expf(glast_all[n] - gc_all[n][vrow]);  // per-token kv weight
    vt[vt_off(vc0 + 0, vrow)] = (bf16)vpf.x;
    vt[vt_off(vc0 + 1, vrow)] = (bf16)vpf.y;
    vt[vt_off(vc0 + 2, vrow)] = (bf16)vpf.z;
    vt[vt_off(vc0 + 3, vrow)] = (bf16)vpf.w;
    vwt[vt_off(vc0 + 0, vrow)] = (bf16)(vpf.x * wv);
    vwt[vt_off(vc0 + 1, vrow)] = (bf16)(vpf.y * wv);
    vwt[vt_off(vc0 + 2, vrow)] = (bf16)(vpf.z * wv);
    vwt[vt_off(vc0 + 3, vrow)] = (bf16)(vpf.w * wv);
  };

  // state: Sa = S[kd = wave*16 + r0+r][vc = jc], Sb at vc = 16+jc
  f32x4 Sa = {0.f, 0.f, 0.f, 0.f}, Sb = {0.f, 0.f, 0.f, 0.f};

  // ---- prologue: issue chunk-0 loads, then scan ALL 64 chunk gates once
  loadpf(0);
#pragma unroll 1
  for (int i = 0; i < 8; ++i) {   // wave w scans chunks w*8 .. w*8+7
    int cn = wave * 8 + i;
    float a = gg[gbase + cn * BT + lane];
#pragma unroll
    for (int off = 1; off < 64; off <<= 1) {
      float t = __shfl_up(a, off);
      if (lane >= off) a += t;
    }
    gc_all[cn][lane] = a;
    if (lane == 63) glast_all[cn] = a;
  }
  LGKM_BARRIER();        // gc_all visible
  stage(0, 0);
  LGKM_BARRIER();

  for (int n = 0; n < NCHUNK; ++n) {
    const int cur = n & 1;

    // ---------- phase 1 ----------
    if (n + 1 < NCHUNK) loadpf(n + 1);  // in flight across barriers (vmcnt not drained)

    // q fragments for chunk n (B for QK^T, A for o_inter)
    bf16x8 af[4];
#pragma unroll
    for (int ks = 0; ks < 4; ++ks)
      af[ks] = frag_row(q_s, QSTR, it * 16, ks * 32, lane);

    // export pre-update state h_n (b64 stores)
    st4(&svt_s[jc * SVSTR + wave * 16 + r0], Sa[0], Sa[1], Sa[2], Sa[3]);
    st4(&svt_s[(16 + jc) * SVSTR + wave * 16 + r0], Sb[0], Sb[1], Sb[2], Sb[3]);

    // s^T = k q^T: lane holds rows j = jt*16+r0+r, col i = it*16+jc
    f32x4 sa0 = {0.f,0.f,0.f,0.f}, sa1 = {0.f,0.f,0.f,0.f};
#pragma unroll
    for (int ks = 0; ks < 4; ++ks) {
      bf16x8 a0 = krow_frag(k_s, jt0 * 16, ks * 32, lane);
      bf16x8 a1 = krow_frag(k_s, (jt0 + 1) * 16, ks * 32, lane);
      sa0 = MFMA(a0, af[ks], sa0, 0, 0, 0);
      sa1 = MFMA(a1, af[ks], sa1, 0, 0, 0);
    }
    {
      int i0 = it * 16 + jc;
      float gci = gc_all[n][i0];
#pragma unroll
      for (int t = 0; t < 2; ++t) {
        f32x4 sv = t ? sa1 : sa0;
        int jb = (jt0 + t) * 16 + r0;
        float4 g4v = *(const float4*)&gc_all[n][jb];
        const float* gj = (const float*)&g4v;
        bf16x4 pk;
#pragma unroll
        for (int r = 0; r < 4; ++r) {
          float val = (i0 >= jb + r) ? sv[r] * __expf(gci - gj[r]) * SCALE : 0.f;
          pk[r] = (bf16)val;
        }
        *(bf16x4*)&sh_s[i0 * SHSTR + jb] = pk;
      }
    }
    // state update: S = decay*S + k^T @ (v*w)
    {
      float dec = __expf(glast_all[n]);
#pragma unroll
      for (int r = 0; r < 4; ++r) { Sa[r] *= dec; Sb[r] *= dec; }
#pragma unroll
      for (int ks = 0; ks < 2; ++ks) {
        bf16x8 a = kcol_frag(k_s, ks * 32 + (g4 << 3), wave * 16 + jc);
        bf16x8 b0 = *(const bf16x8*)(&vwT_s[cur][0] + vt_off(jc, ks * 32 + (g4 << 3)));
        bf16x8 b1 = *(const bf16x8*)(&vwT_s[cur][0] + vt_off(16 + jc, ks * 32 + (g4 << 3)));
        Sa = MFMA(a, b0, Sa, 0, 0, 0);
        Sb = MFMA(a, b1, Sb, 0, 0, 0);
      }
    }
    LGKM_BARRIER();

    // ---------- phase 2 ----------
    {
      f32x4 oacc = {0.f, 0.f, 0.f, 0.f};
#pragma unroll
      for (int ks = 0; ks < 4; ++ks) {  // o_inter = q @ h_n
        bf16x8 b = frag_row(svt_s, SVSTR, nt * 16, ks * 32, lane);
        oacc = MFMA(af[ks], b, oacc, 0, 0, 0);
      }
      {
        float4 e4 = *(const float4*)&gc_all[n][it * 16 + r0];
        const float* ep = (const float*)&e4;
#pragma unroll
        for (int r = 0; r < 4; ++r) oacc[r] *= __expf(ep[r]) * SCALE;
      }
#pragma unroll
      for (int ks = 0; ks < 2; ++ks) {  // o_intra = s-hat @ v
        bf16x8 a = frag_row(sh_s, SHSTR, it * 16, ks * 32, lane);
        bf16x8 b = *(const bf16x8*)(&vT_s[cur][0] + vt_off(nt * 16 + jc, ks * 32 + (g4 << 3)));
        oacc = MFMA(a, b, oacc, 0, 0, 0);
      }
#pragma unroll
      for (int r = 0; r < 4; ++r) {
        int row = it * 16 + r0 + r;
        og[vbase + (size_t)(n * BT + row) * VD + nt * 16 + jc] = oacc[r];
      }
    }
    if (n + 1 < NCHUNK) stage((n + 1) & 1, n + 1);  // q_s/k_s free after P1
    LGKM_BARRIER();
  }
}

extern "C" void kernel_launch(void* const* d_in, const int* in_sizes, int n_in,
                              void* d_out, int out_size, void* d_ws, size_t ws_size,
                              hipStream_t stream) {
  const float* q = (const float*)d_in[0];
  const float* k = (const float*)d_in[1];
  const float* v = (const float*)d_in[2];
  const float* g = (const float*)d_in[3];
  float* o = (float*)d_out;
  dim3 grid(256);   // 64 (b,h) x 4 v-segments
  dim3 block(512);  // 8 waves
  gla_fused<<<grid, block, 0, stream>>>(q, k, v, g, o);
}

// Round 6
// 161.949 us; speedup vs baseline: 1.4253x; 1.1488x over previous
//
#include <hip/hip_runtime.h>
#include <hip/hip_bf16.h>

// Chunked simple-GLA forward, B=2 H=32 T=4096 K=V=128, BT=64.
// grid = 64 (b,h) x 4 v-segments, 512 threads (8 waves).
// State slice S [128 kd x 32 vc] lives in MFMA accumulators.
// SINGLE barrier per chunk: iteration n overlaps
//   o-emit(n-1)  ||  QK^T+gate+state(n)  ||  stage(n+1)+loads(n+2).
// q/k/sh/svt double-buffered; vT/vwT triple-buffered; q-frags carried in regs.

#define BT 64
#define KD 128
#define VD 128
#define VSG 32
#define NCHUNK 64
#define TLEN 4096
#define SCALE 0.08838834764831845f   // 128^-0.5

#define QSTR 136   // q_s/k_s row stride (elems)
#define SHSTR 72
#define SVSTR 136
#define VTSTR 72

typedef __bf16 bf16;
typedef __bf16 bf16x8 __attribute__((ext_vector_type(8)));
typedef __bf16 bf16x4 __attribute__((ext_vector_type(4)));
typedef float f32x4 __attribute__((ext_vector_type(4)));

#define MFMA __builtin_amdgcn_mfma_f32_16x16x32_bf16
#define LGKM_BARRIER() do { asm volatile("s_waitcnt lgkmcnt(0)" ::: "memory"); \
                            __builtin_amdgcn_s_barrier(); } while (0)

// k_s byte swizzle: key (t>>3)&3 == lane-group of the column reads -> 2-way
__device__ __forceinline__ int ksw(int t) { return ((t >> 3) & 3) << 5; }

// vT/vwT swizzle: conflict-free transposed stores, b128-aligned reads
__device__ __forceinline__ int vt_off(int vc, int t) {
  int byte = vc * (VTSTR * 2) + t * 2;
  byte ^= ((vc >> 2) & 7) << 4;
  return byte >> 1;
}

// row fragment (non-swizzled: q_s, svt, sh)
__device__ __forceinline__ bf16x8 frag_row(const bf16* p, int stride, int row0,
                                           int kk0, int lane) {
  int row = row0 + (lane & 15);
  int kk = kk0 + ((lane >> 4) << 3);
  return *(const bf16x8*)(p + row * stride + kk);
}

// swizzled k_s row fragment (QK^T A operand)
__device__ __forceinline__ bf16x8 krow_frag(const bf16* ks_, int row0, int kk0,
                                            int lane) {
  int row = row0 + (lane & 15);
  int kk = kk0 + ((lane >> 4) << 3);
  int byte = (row * (QSTR * 2) + kk * 2) ^ ksw(row);
  return *(const bf16x8*)((const char*)ks_ + byte);
}

// swizzled k_s column fragment (state-update A operand), 8 scalar 2-way reads
__device__ __forceinline__ bf16x8 kcol_frag(const bf16* ks_, int T0, int kdA) {
  int C = ((T0 >> 3) & 3) << 5;
  int b0 = T0 * (QSTR * 2) + kdA * 2;
  bf16x8 f;
#pragma unroll
  for (int j = 0; j < 8; ++j)
    f[j] = *(const bf16*)((const char*)ks_ + ((b0 + j * (QSTR * 2)) ^ C));
  return f;
}

__device__ __forceinline__ void st4(bf16* p, float a, float b, float c, float d) {
  bf16x4 t;
  t[0] = (bf16)a; t[1] = (bf16)b; t[2] = (bf16)c; t[3] = (bf16)d;
  *(bf16x4*)p = t;
}

__global__ void __launch_bounds__(512, 2)
gla_fused(const float* __restrict__ qg, const float* __restrict__ kg,
          const float* __restrict__ vg, const float* __restrict__ gg,
          float* __restrict__ og)
{
  __shared__ __align__(16) bf16 q_s[2][BT * QSTR];     // 34.8 KB
  __shared__ __align__(16) bf16 k_s[2][BT * QSTR];     // 34.8 KB (swizzled)
  __shared__ __align__(16) bf16 vT_s[3][VSG * VTSTR];  // 13.8 KB
  __shared__ __align__(16) bf16 vwT_s[3][VSG * VTSTR]; // 13.8 KB
  __shared__ __align__(16) bf16 sh_s[2][BT * SHSTR];   // 18.4 KB
  __shared__ __align__(16) bf16 svt_s[2][VSG * SVSTR]; // 17.4 KB
  __shared__ __align__(16) float gc_all[NCHUNK][BT];   // 16.4 KB
  __shared__ float glast_all[NCHUNK];                  // total ~149.8 KB

  const int tid = threadIdx.x;
  const int wave = tid >> 6;
  const int lane = tid & 63;
  const int bh = blockIdx.x & 63;   // 4 vseg blocks of one bh share an XCD
  const int vseg = blockIdx.x >> 6;

  const int jc = lane & 15;
  const int g4 = lane >> 4;
  const int r0 = g4 << 2;

  const int it = wave & 3;             // q-token tile (s cols, o rows)
  const int nt = wave >> 2;            // o vcol tile
  const int jt0 = (wave < 4) ? 0 : 2;  // k-token tiles {jt0, jt0+1}

  const size_t qkbase = (size_t)bh * TLEN * KD;
  const size_t gbase = (size_t)bh * TLEN;
  const size_t vbase = (size_t)bh * TLEN * VD + (size_t)vseg * VSG;
  const int vrow = tid >> 3;
  const int vc0 = (tid & 7) << 2;

  float4 qpf[4], kpf[4], vpf;

  auto loadpf = [&](int n) {  // coalesced float4 loads for chunk n
    const float4* q4 = (const float4*)(qg + qkbase + (size_t)n * (BT * KD));
    const float4* k4 = (const float4*)(kg + qkbase + (size_t)n * (BT * KD));
#pragma unroll
    for (int i = 0; i < 4; ++i) { qpf[i] = q4[i * 512 + tid]; kpf[i] = k4[i * 512 + tid]; }
    vpf = *(const float4*)(vg + vbase + (size_t)(n * BT + vrow) * VD + vc0);
  };

  auto stage = [&](int b2, int b3, int n) {  // q_s[b2], k_s[b2], vT/vwT[b3]
#pragma unroll
    for (int i = 0; i < 4; ++i) {
      int f4 = i * 512 + tid;
      int t = f4 >> 5;
      int kd0 = (f4 & 31) << 2;
      st4(&q_s[b2][t * QSTR + kd0], qpf[i].x, qpf[i].y, qpf[i].z, qpf[i].w);
      int byte = (t * (QSTR * 2) + kd0 * 2) ^ ksw(t);
      st4((bf16*)((char*)k_s[b2] + byte), kpf[i].x, kpf[i].y, kpf[i].z, kpf[i].w);
    }
    bf16* vt = vT_s[b3];
    bf16* vwt = vwT_s[b3];
    float wv = __expf(glast_all[n] - gc_all[n][vrow]);  // per-token kv weight
    vt[vt_off(vc0 + 0, vrow)] = (bf16)vpf.x;
    vt[vt_off(vc0 + 1, vrow)] = (bf16)vpf.y;
    vt[vt_off(vc0 + 2, vrow)] = (bf16)vpf.z;
    vt[vt_off(vc0 + 3, vrow)] = (bf16)vpf.w;
    vwt[vt_off(vc0 + 0, vrow)] = (bf16)(vpf.x * wv);
    vwt[vt_off(vc0 + 1, vrow)] = (bf16)(vpf.y * wv);
    vwt[vt_off(vc0 + 2, vrow)] = (bf16)(vpf.z * wv);
    vwt[vt_off(vc0 + 3, vrow)] = (bf16)(vpf.w * wv);
  };

  auto o_emit = [&](int no, int b2o, int b3o, const bf16x8 (&afp)[4]) {
    f32x4 oacc = {0.f, 0.f, 0.f, 0.f};
#pragma unroll
    for (int ks = 0; ks < 4; ++ks) {  // o_inter = q @ h_no
      bf16x8 b = frag_row(svt_s[b2o], SVSTR, nt * 16, ks * 32, lane);
      oacc = MFMA(afp[ks], b, oacc, 0, 0, 0);
    }
    {
      float4 e4 = *(const float4*)&gc_all[no][it * 16 + r0];
      const float* ep = (const float*)&e4;
#pragma unroll
      for (int r = 0; r < 4; ++r) oacc[r] *= __expf(ep[r]) * SCALE;
    }
#pragma unroll
    for (int ks = 0; ks < 2; ++ks) {  // o_intra = s-hat @ v
      bf16x8 a = frag_row(sh_s[b2o], SHSTR, it * 16, ks * 32, lane);
      bf16x8 b = *(const bf16x8*)(vT_s[b3o] + vt_off(nt * 16 + jc, ks * 32 + (g4 << 3)));
      oacc = MFMA(a, b, oacc, 0, 0, 0);
    }
#pragma unroll
    for (int r = 0; r < 4; ++r) {
      int row = it * 16 + r0 + r;
      og[vbase + (size_t)(no * BT + row) * VD + nt * 16 + jc] = oacc[r];
    }
  };

  // state: Sa = S[kd = wave*16 + r0+r][vc = jc], Sb at vc = 16+jc
  f32x4 Sa = {0.f, 0.f, 0.f, 0.f}, Sb = {0.f, 0.f, 0.f, 0.f};
  bf16x8 afp[4];  // q fragments of the previous chunk (for o_inter)

  // ---- prologue: chunk-0 loads + all 64 gate scans
  loadpf(0);
#pragma unroll 1
  for (int i = 0; i < 8; ++i) {   // wave w scans chunks w*8 .. w*8+7
    int cn = wave * 8 + i;
    float a = gg[gbase + cn * BT + lane];
#pragma unroll
    for (int off = 1; off < 64; off <<= 1) {
      float t = __shfl_up(a, off);
      if (lane >= off) a += t;
    }
    gc_all[cn][lane] = a;
    if (lane == 63) glast_all[cn] = a;
  }
  LGKM_BARRIER();        // gc_all visible
  stage(0, 0, 0);
  loadpf(1);
  LGKM_BARRIER();        // chunk 0 staged

  int b3 = 0;            // n % 3
#pragma unroll 1
  for (int n = 0; n < NCHUNK; ++n) {
    const int b2 = n & 1;
    const int b3n = (b3 == 2) ? 0 : b3 + 1;   // (n+1) % 3
    const int b3p = (b3 == 0) ? 2 : b3 - 1;   // (n-1) % 3

    // ---- o for chunk n-1 (all inputs written before last barrier)
    if (n > 0) o_emit(n - 1, b2 ^ 1, b3p, afp);

    // ---- q fragments for chunk n (kept in regs for next iter's o_inter)
    bf16x8 af[4];
#pragma unroll
    for (int ks = 0; ks < 4; ++ks)
      af[ks] = frag_row(q_s[b2], QSTR, it * 16, ks * 32, lane);

    // ---- s^T = k q^T -> gated s-hat into sh_s[b2]
    f32x4 sa0 = {0.f,0.f,0.f,0.f}, sa1 = {0.f,0.f,0.f,0.f};
#pragma unroll
    for (int ks = 0; ks < 4; ++ks) {
      bf16x8 a0 = krow_frag(k_s[b2], jt0 * 16, ks * 32, lane);
      bf16x8 a1 = krow_frag(k_s[b2], (jt0 + 1) * 16, ks * 32, lane);
      sa0 = MFMA(a0, af[ks], sa0, 0, 0, 0);
      sa1 = MFMA(a1, af[ks], sa1, 0, 0, 0);
    }
    {
      int i0 = it * 16 + jc;
      float gci = gc_all[n][i0];
#pragma unroll
      for (int t = 0; t < 2; ++t) {
        f32x4 sv = t ? sa1 : sa0;
        int jb = (jt0 + t) * 16 + r0;
        float4 g4v = *(const float4*)&gc_all[n][jb];
        const float* gj = (const float*)&g4v;
        bf16x4 pk;
#pragma unroll
        for (int r = 0; r < 4; ++r) {
          float val = (i0 >= jb + r) ? sv[r] * __expf(gci - gj[r]) * SCALE : 0.f;
          pk[r] = (bf16)val;
        }
        *(bf16x4*)&sh_s[b2][i0 * SHSTR + jb] = pk;
      }
    }

    // ---- export h_n (pre-update state), then state update with chunk n
    st4(&svt_s[b2][jc * SVSTR + wave * 16 + r0], Sa[0], Sa[1], Sa[2], Sa[3]);
    st4(&svt_s[b2][(16 + jc) * SVSTR + wave * 16 + r0], Sb[0], Sb[1], Sb[2], Sb[3]);
    {
      float dec = __expf(glast_all[n]);
#pragma unroll
      for (int r = 0; r < 4; ++r) { Sa[r] *= dec; Sb[r] *= dec; }
#pragma unroll
      for (int ks = 0; ks < 2; ++ks) {
        bf16x8 a = kcol_frag(k_s[b2], ks * 32 + (g4 << 3), wave * 16 + jc);
        bf16x8 b0 = *(const bf16x8*)(vwT_s[b3] + vt_off(jc, ks * 32 + (g4 << 3)));
        bf16x8 b1 = *(const bf16x8*)(vwT_s[b3] + vt_off(16 + jc, ks * 32 + (g4 << 3)));
        Sa = MFMA(a, b0, Sa, 0, 0, 0);
        Sb = MFMA(a, b1, Sb, 0, 0, 0);
      }
    }

    // ---- stage chunk n+1, then issue HBM loads for chunk n+2
    if (n + 1 < NCHUNK) {
      stage(b2 ^ 1, b3n, n + 1);
      if (n + 2 < NCHUNK) loadpf(n + 2);
    }

#pragma unroll
    for (int ks = 0; ks < 4; ++ks) afp[ks] = af[ks];
    b3 = b3n;

    LGKM_BARRIER();   // the ONLY barrier per chunk
  }

  // ---- epilogue: o for the last chunk (63&1=1, 63%3=0)
  o_emit(NCHUNK - 1, 1, 0, afp);
}

extern "C" void kernel_launch(void* const* d_in, const int* in_sizes, int n_in,
                              void* d_out, int out_size, void* d_ws, size_t ws_size,
                              hipStream_t stream) {
  const float* q = (const float*)d_in[0];
  const float* k = (const float*)d_in[1];
  const float* v = (const float*)d_in[2];
  const float* g = (const float*)d_in[3];
  float* o = (float*)d_out;
  dim3 grid(256);   // 64 (b,h) x 4 v-segments
  dim3 block(512);  // 8 waves
  gla_fused<<<grid, block, 0, stream>>>(q, k, v, g, o);
}